// Round 4
// baseline (289.253 us; speedup 1.0000x reference)
//
#include <hip/hip_runtime.h>
#include <hip/hip_bf16.h>

constexpr int D_ = 128;
constexpr int DK_ = 16;
constexpr int TBL = 16384;

typedef __attribute__((ext_vector_type(8))) short short8;
typedef __attribute__((ext_vector_type(4))) float f32x4;

__device__ __forceinline__ ushort f2b(float f) {
    uint b = __float_as_uint(f);
    uint r = (b + 0x7fffu + ((b >> 16) & 1u)) >> 16;
    return (ushort)r;
}
__device__ __forceinline__ float blo(uint u) { return __uint_as_float(u << 16); }
__device__ __forceinline__ float bhi(uint u) { return __uint_as_float(u & 0xffff0000u); }

__device__ __forceinline__ float fexp2(float x) {
#if __has_builtin(__builtin_amdgcn_exp2f)
    return __builtin_amdgcn_exp2f(x);
#else
    return exp2f(x);
#endif
}
__device__ __forceinline__ float frcp(float x) {
#if __has_builtin(__builtin_amdgcn_rcpf)
    return __builtin_amdgcn_rcpf(x);
#else
    return 1.0f / x;
#endif
}

// ---------------- detect int64 vs int32 edge_index layout ----------------
__global__ void k_detect(const int* __restrict__ ei, int* __restrict__ flag) {
    __shared__ int sor;
    if (threadIdx.x == 0) sor = 0;
    __syncthreads();
    int v = 0;
    for (int k = threadIdx.x; k < 1024; k += blockDim.x) v |= ei[2 * k + 1];
    atomicOr(&sor, v);
    __syncthreads();
    if (threadIdx.x == 0) flag[0] = (sor == 0) ? 1 : 0;  // 1 => int64 layout
}

__device__ __forceinline__ void load_edge(const int* __restrict__ ei, int E, int f64,
                                          int e, int& s, int& dd) {
    if (f64) { s = ei[2 * e]; dd = ei[2 * E + 2 * e]; }
    else     { s = ei[e];     dd = ei[E + e]; }
}

// ---------------- WTb[384][128] bf16 (B^T layout), BB[384] f32 ----------------
__global__ void k_wprep(const float* __restrict__ Wq, const float* __restrict__ bq,
                        const float* __restrict__ Wk, const float* __restrict__ bk,
                        const float* __restrict__ Wv, const float* __restrict__ bv,
                        ushort* __restrict__ WTb, float* __restrict__ BB) {
    int idx = blockIdx.x * blockDim.x + threadIdx.x;
    int total = 384 * 128;
    for (int i = idx; i < total; i += gridDim.x * blockDim.x) {
        int c = i >> 7;
        int d = i & 127;
        int m = c >> 7;
        int cl = c & 127;
        int h = cl >> 4, kk = cl & 15;
        const float* W = (m == 0) ? Wq : ((m == 1) ? Wk : Wv);
        WTb[i] = f2b(W[(h * D_ + d) * DK_ + kk]);
    }
    if (idx < 384) {
        int m = idx >> 7, cl = idx & 127;
        const float* b = (m == 0) ? bq : ((m == 1) ? bk : bv);
        BB[idx] = b[cl];
    }
}

// ---------------- LayerNorm -> bf16 xnb ----------------
__global__ __launch_bounds__(256)
void k_ln(const float2* __restrict__ x2, uint* __restrict__ xnb, int N) {
    int row = blockIdx.x * 4 + (threadIdx.x >> 6);
    if (row >= N) return;
    int lane = threadIdx.x & 63;
    float2 v = x2[(size_t)row * 64 + lane];
    float s = v.x + v.y;
    #pragma unroll
    for (int o = 1; o < 64; o <<= 1) s += __shfl_xor(s, o);
    float mu = s * (1.0f / 128.0f);
    float dx = v.x - mu, dy = v.y - mu;
    float s2 = dx * dx + dy * dy;
    #pragma unroll
    for (int o = 1; o < 64; o <<= 1) s2 += __shfl_xor(s2, o);
    float rs = rsqrtf(s2 * (1.0f / 128.0f) + 1e-5f);
    uint lo = f2b(dx * rs), hi = f2b(dy * rs);
    xnb[(size_t)row * 64 + lane] = (hi << 16) | lo;
}

// ---------------- MFMA GEMM: [N x 128] bf16 x [128 x 384] -> qnb / kvb(interleaved) ----------------
// grid: (ceil(N/128), 3); block 256 = 4 waves (2x2), wave computes 64x64
__global__ __launch_bounds__(256)
void k_gemm(const ushort* __restrict__ xnb, const ushort* __restrict__ WTb,
            const float* __restrict__ BB,
            ushort* __restrict__ qnb, ushort* __restrict__ kvb,
            int N) {
    __shared__ short As[128 * 128];
    __shared__ short Bs[128 * 128];
    int tid = threadIdx.x;
    int rowBlk = blockIdx.x, cb = blockIdx.y;

    short8 av[8], bv[8];
    int chunk = tid & 15;
    #pragma unroll
    for (int i = 0; i < 8; ++i) {
        int row = i * 16 + (tid >> 4);
        int gRow = rowBlk * 128 + row;
        if (gRow < N) av[i] = *(const short8*)(xnb + (size_t)gRow * 128 + chunk * 8);
        else          av[i] = short8{0, 0, 0, 0, 0, 0, 0, 0};
        int gCol = cb * 128 + row;
        bv[i] = *(const short8*)(WTb + (size_t)gCol * 128 + chunk * 8);
    }
    #pragma unroll
    for (int i = 0; i < 8; ++i) {
        int row = i * 16 + (tid >> 4);
        int widx = row * 128 + ((chunk * 8) ^ ((row & 7) * 8));
        *(short8*)&As[widx] = av[i];
        *(short8*)&Bs[widx] = bv[i];
    }
    __syncthreads();

    int wv = tid >> 6, lane = tid & 63;
    int wr = wv >> 1, wc = wv & 1;
    int l15 = lane & 15, g = lane >> 4;

    f32x4 acc[4][4];
    #pragma unroll
    for (int m = 0; m < 4; ++m)
        #pragma unroll
        for (int n = 0; n < 4; ++n) acc[m][n] = f32x4{0.f, 0.f, 0.f, 0.f};

    #pragma unroll
    for (int kt = 0; kt < 4; ++kt) {
        int kshort = kt * 32 + g * 8;
        short8 af[4], bf[4];
        #pragma unroll
        for (int m = 0; m < 4; ++m) {
            int r = wr * 64 + m * 16 + l15;
            af[m] = *(const short8*)&As[r * 128 + (kshort ^ ((r & 7) * 8))];
        }
        #pragma unroll
        for (int n = 0; n < 4; ++n) {
            int c = wc * 64 + n * 16 + l15;
            bf[n] = *(const short8*)&Bs[c * 128 + (kshort ^ ((c & 7) * 8))];
        }
        #pragma unroll
        for (int m = 0; m < 4; ++m)
            #pragma unroll
            for (int n = 0; n < 4; ++n)
                acc[m][n] = __builtin_amdgcn_mfma_f32_16x16x32_bf16(af[m], bf[n], acc[m][n], 0, 0, 0);
    }

    float bb[4];
    #pragma unroll
    for (int n = 0; n < 4; ++n) bb[n] = BB[cb * 128 + wc * 64 + n * 16 + l15];

    #pragma unroll
    for (int m = 0; m < 4; ++m) {
        int R0 = rowBlk * 128 + wr * 64 + m * 16 + g * 4;
        #pragma unroll
        for (int n = 0; n < 4; ++n) {
            int cl = wc * 64 + n * 16 + l15;
            #pragma unroll
            for (int r = 0; r < 4; ++r) {
                int row = R0 + r;
                if (row >= N) continue;
                float val = acc[m][n][r] + bb[n];
                if (cb == 0) {
                    qnb[(size_t)row * 128 + cl] = f2b(val);
                } else {
                    // interleaved kv: uint-pair granularity [k2d, v2d, k2d, v2d, ...]
                    int off = ((cl >> 1) << 2) + (cl & 1) + ((cb == 2) ? 2 : 0);
                    kvb[(size_t)row * 256 + off] = f2b(val);
                }
            }
        }
    }
}

// ---------------- degree over senders + count over receivers ----------------
__global__ void k_deg_count(const int* __restrict__ ei, const float* __restrict__ w,
                            const int* __restrict__ flag, float* __restrict__ deg,
                            int* __restrict__ cnt, int E) {
    int f64 = flag[0];
    int i = blockIdx.x * blockDim.x + threadIdx.x;
    int stride = gridDim.x * blockDim.x;
    for (int e = i; e < E; e += stride) {
        int s, dd;
        load_edge(ei, E, f64, e, s, dd);
        atomicAdd(&deg[s], w[e]);
        atomicAdd(&cnt[dd], 1);
    }
}

// ---------------- temporal table -> bf16 gkv[TBL][256] interleaved (nearest-sample) ----------------
__global__ __launch_bounds__(128)
void k_table(const float* __restrict__ Wk, const float* __restrict__ Wv,
             ushort* __restrict__ gkv) {
    __shared__ float te[8][128];
    int j = threadIdx.x;
    int t0 = blockIdx.x * 8;
    float freq = 200.0f * exp2f(-(float)(j >> 1) * (13.287712379549449f / 64.0f));
    bool isCos = (j & 1);
    #pragma unroll
    for (int b = 0; b < 8; ++b) {
        float t = (float)(t0 + b) * (1.0f / (float)(TBL - 1));
        float arg = t * freq;
        te[b][j] = isCos ? cosf(arg) : sinf(arg);
    }
    __syncthreads();
    int h = j >> 4, kk = j & 15;
    float ak[8] = {}, av[8] = {};
    for (int d = 0; d < 128; ++d) {
        float wk = Wk[(h * 128 + d) * 16 + kk];
        float wv = Wv[(h * 128 + d) * 16 + kk];
        float tvs[8];
        #pragma unroll
        for (int b = 0; b < 8; ++b) tvs[b] = te[b][d];
        #pragma unroll
        for (int b = 0; b < 8; ++b) { ak[b] += tvs[b] * wk; av[b] += tvs[b] * wv; }
    }
    int off = ((j >> 1) << 2) + (j & 1);
    #pragma unroll
    for (int b = 0; b < 8; ++b) {
        gkv[(size_t)(t0 + b) * 256 + off]     = f2b(ak[b]);
        gkv[(size_t)(t0 + b) * 256 + off + 2] = f2b(av[b]);
    }
}

// ---------------- 3-kernel exclusive scan over cnt -> rowptr ----------------
__global__ __launch_bounds__(256)
void k_scanA(const int* __restrict__ cnt, int* __restrict__ csum) {
    __shared__ int sh[256];
    int b = blockIdx.x, t = threadIdx.x;
    int base = b * 1024 + t * 4;
    int s = cnt[base] + cnt[base + 1] + cnt[base + 2] + cnt[base + 3];
    sh[t] = s;
    __syncthreads();
    for (int off = 128; off > 0; off >>= 1) {
        if (t < off) sh[t] += sh[t + off];
        __syncthreads();
    }
    if (t == 0) csum[b] = sh[0];
}

__global__ void k_scanB(int* __restrict__ csum, int nch) {
    if (blockIdx.x == 0 && threadIdx.x == 0) {
        int run = 0;
        for (int i = 0; i < nch; ++i) { int v = csum[i]; csum[i] = run; run += v; }
    }
}

__global__ __launch_bounds__(256)
void k_scanC(const int* __restrict__ cnt, const int* __restrict__ csum,
             int* __restrict__ rowptr) {
    __shared__ int sh[256];
    int b = blockIdx.x, t = threadIdx.x;
    int base = b * 1024 + t * 4;
    int v0 = cnt[base], v1 = cnt[base + 1], v2 = cnt[base + 2], v3 = cnt[base + 3];
    int tot = v0 + v1 + v2 + v3;
    sh[t] = tot;
    __syncthreads();
    for (int off = 1; off < 256; off <<= 1) {
        int add = (t >= off) ? sh[t - off] : 0;
        __syncthreads();
        sh[t] += add;
        __syncthreads();
    }
    int excl = sh[t] - tot + csum[b];
    rowptr[base]     = excl;
    rowptr[base + 1] = excl + v0;
    rowptr[base + 2] = excl + v0 + v1;
    rowptr[base + 3] = excl + v0 + v1 + v2;
}

// ---------------- scatter packed edge records into dst-CSR buckets ----------------
// record: {src, table_idx, ew * 0.25 * log2(e) as float bits, 0}
__global__ void k_scatter(const int* __restrict__ ei, const float* __restrict__ ewt,
                          const float* __restrict__ etime, const int* __restrict__ flag,
                          const float* __restrict__ deg,
                          int* __restrict__ cursor, uint4* __restrict__ erec, int E) {
    const float C = 0.25f * 1.4426950408889634f;
    int f64 = flag[0];
    int i = blockIdx.x * blockDim.x + threadIdx.x;
    int stride = gridDim.x * blockDim.x;
    for (int e = i; e < E; e += stride) {
        int s, dd;
        load_edge(ei, E, f64, e, s, dd);
        int pos = atomicAdd(&cursor[dd], 1);
        float t = etime[e];
        int ti = (int)(t * (float)(TBL - 1) + 0.5f);
        ti = ti < 0 ? 0 : (ti > TBL - 1 ? TBL - 1 : ti);
        float dg = deg[s];
        float ewc = dg > 0.f ? ewt[e] * C / dg : 0.f;
        uint4 r;
        r.x = (uint)s; r.y = (uint)ti; r.z = __float_as_uint(ewc); r.w = 0;
        erec[pos] = r;
    }
}

// ---------------- fused per-node attention + aggregation + residual + GELU ----------------
// one 64-lane wave per destination node; lane covers dims {2*lane, 2*lane+1}
__global__ __launch_bounds__(256)
void k_aggr(const int* __restrict__ rowptr, const uint4* __restrict__ erec,
            const ushort* __restrict__ qnb, const ushort* __restrict__ kvb,
            const ushort* __restrict__ gkv,
            const float2* __restrict__ x2, float2* __restrict__ out2, int N) {
    int w = (int)((blockIdx.x * (size_t)blockDim.x + threadIdx.x) >> 6);
    if (w >= N) return;
    int lane = threadIdx.x & 63;
    uint qv = *(const uint*)(qnb + (size_t)w * 128 + 2 * lane);
    float qx = blo(qv), qy = bhi(qv);
    float nx = 0.f, ny = 0.f, den = 0.f;
    int beg = rowptr[w], end = rowptr[w + 1];

    int j = beg;
    for (; j + 2 <= end; j += 2) {
        uint4 r0 = erec[j], r1 = erec[j + 1];
        uint2 kv0 = *(const uint2*)(kvb + (size_t)r0.x * 256 + 4 * lane);
        uint2 g0  = *(const uint2*)(gkv + (size_t)r0.y * 256 + 4 * lane);
        uint2 kv1 = *(const uint2*)(kvb + (size_t)r1.x * 256 + 4 * lane);
        uint2 g1  = *(const uint2*)(gkv + (size_t)r1.y * 256 + 4 * lane);

        float kx0 = blo(kv0.x) + blo(g0.x), ky0 = bhi(kv0.x) + bhi(g0.x);
        float kx1 = blo(kv1.x) + blo(g1.x), ky1 = bhi(kv1.x) + bhi(g1.x);
        float p0 = kx0 * qx + ky0 * qy;
        float p1 = kx1 * qx + ky1 * qy;
        p0 += __shfl_xor(p0, 1); p1 += __shfl_xor(p1, 1);
        p0 += __shfl_xor(p0, 2); p1 += __shfl_xor(p1, 2);
        p0 += __shfl_xor(p0, 4); p1 += __shfl_xor(p1, 4);
        float ex0 = fexp2(p0 * __uint_as_float(r0.z));
        float ex1 = fexp2(p1 * __uint_as_float(r1.z));
        den += ex0 + ex1;
        nx += ex0 * (blo(kv0.y) + blo(g0.y)) + ex1 * (blo(kv1.y) + blo(g1.y));
        ny += ex0 * (bhi(kv0.y) + bhi(g0.y)) + ex1 * (bhi(kv1.y) + bhi(g1.y));
    }
    if (j < end) {
        uint4 r0 = erec[j];
        uint2 kv0 = *(const uint2*)(kvb + (size_t)r0.x * 256 + 4 * lane);
        uint2 g0  = *(const uint2*)(gkv + (size_t)r0.y * 256 + 4 * lane);
        float kx0 = blo(kv0.x) + blo(g0.x), ky0 = bhi(kv0.x) + bhi(g0.x);
        float p0 = kx0 * qx + ky0 * qy;
        p0 += __shfl_xor(p0, 1);
        p0 += __shfl_xor(p0, 2);
        p0 += __shfl_xor(p0, 4);
        float ex0 = fexp2(p0 * __uint_as_float(r0.z));
        den += ex0;
        nx += ex0 * (blo(kv0.y) + blo(g0.y));
        ny += ex0 * (bhi(kv0.y) + bhi(g0.y));
    }

    float inv = den > 0.f ? frcp(den) : 0.f;
    nx *= inv; ny *= inv;
    float2 xx = x2[(size_t)w * 64 + lane];
    float2 o;
    o.x = xx.x + 0.5f * nx * (1.0f + erff(nx * 0.70710678118f));
    o.y = xx.y + 0.5f * ny * (1.0f + erff(ny * 0.70710678118f));
    out2[(size_t)w * 64 + lane] = o;
}

extern "C" void kernel_launch(void* const* d_in, const int* in_sizes, int n_in,
                              void* d_out, int out_size, void* d_ws, size_t ws_size,
                              hipStream_t stream) {
    const float* x    = (const float*)d_in[0];
    const int*   ei   = (const int*)d_in[1];
    const float* ewt  = (const float*)d_in[2];
    const float* etim = (const float*)d_in[4];
    const float* Wk   = (const float*)d_in[5];
    const float* bk   = (const float*)d_in[6];
    const float* Wq   = (const float*)d_in[7];
    const float* bq   = (const float*)d_in[8];
    const float* Wv   = (const float*)d_in[9];
    const float* bv   = (const float*)d_in[10];
    int N = in_sizes[3];
    int E = in_sizes[2];
    float* out = (float*)d_out;

    int NCH = (N + 1 + 1023) / 1024;
    int NP = NCH * 1024;

    char* base = (char*)d_ws;
    size_t off = 0;
    auto alloc = [&](size_t bytes) {
        char* r = base + off;
        off += (bytes + 255) & ~size_t(255);
        return r;
    };
    ushort* xnb = (ushort*)alloc((size_t)N * 128 * 2);       // dead after gemm; reused as erec
    ushort* qnb = (ushort*)alloc((size_t)N * 128 * 2);
    ushort* kvb = (ushort*)alloc((size_t)N * 256 * 2);
    ushort* gkv = (ushort*)alloc((size_t)TBL * 256 * 2);
    ushort* WTb = (ushort*)alloc(384 * 128 * 2);
    float*  BB  = (float*)alloc(384 * 4);
    float*  deg = (float*)alloc((size_t)N * 4);
    int*    cnt    = (int*)alloc((size_t)NP * 4);
    int*    rowptr = (int*)alloc((size_t)NP * 4);
    int*    cursor = (int*)alloc((size_t)NP * 4);
    int*    csum   = (int*)alloc((size_t)NCH * 4);
    int*    flag   = (int*)alloc(16);
    uint4*  erec   = (uint4*)xnb;   // E*16 = 10.24MB <= N*256B = 12.8MB

    hipMemsetAsync(deg, 0, (size_t)N * sizeof(float), stream);
    hipMemsetAsync(cnt, 0, (size_t)NP * sizeof(int), stream);

    k_detect<<<1, 256, 0, stream>>>(ei, flag);
    k_wprep<<<64, 256, 0, stream>>>(Wq, bq, Wk, bk, Wv, bv, WTb, BB);
    k_deg_count<<<512, 256, 0, stream>>>(ei, ewt, flag, deg, cnt, E);
    k_table<<<TBL / 8, 128, 0, stream>>>(Wk, Wv, gkv);
    k_ln<<<(N + 3) / 4, 256, 0, stream>>>((const float2*)x, (uint*)xnb, N);

    dim3 ggrid((N + 127) / 128, 3);
    k_gemm<<<ggrid, 256, 0, stream>>>(xnb, WTb, BB, qnb, kvb, N);

    k_scanA<<<NCH, 256, 0, stream>>>(cnt, csum);
    k_scanB<<<1, 64, 0, stream>>>(csum, NCH);
    k_scanC<<<NCH, 256, 0, stream>>>(cnt, csum, rowptr);
    hipMemcpyAsync(cursor, rowptr, (size_t)NP * sizeof(int),
                   hipMemcpyDeviceToDevice, stream);
    k_scatter<<<512, 256, 0, stream>>>(ei, ewt, etim, flag, deg, cursor, erec, E);

    int agrid = (int)(((size_t)N * 64 + 255) / 256);
    k_aggr<<<agrid, 256, 0, stream>>>(rowptr, erec, qnb, kvb, gkv,
                                      (const float2*)x, (float2*)out, N);
}

// Round 5
// 257.641 us; speedup vs baseline: 1.1227x; 1.1227x over previous
//
#include <hip/hip_runtime.h>
#include <hip/hip_bf16.h>

constexpr int D_ = 128;
constexpr int DK_ = 16;
constexpr int TBL = 4096;

typedef __attribute__((ext_vector_type(8))) short short8;
typedef __attribute__((ext_vector_type(4))) float f32x4;

__device__ __forceinline__ ushort f2b(float f) {
    uint b = __float_as_uint(f);
    uint r = (b + 0x7fffu + ((b >> 16) & 1u)) >> 16;
    return (ushort)r;
}
__device__ __forceinline__ float blo(uint u) { return __uint_as_float(u << 16); }
__device__ __forceinline__ float bhi(uint u) { return __uint_as_float(u & 0xffff0000u); }

__device__ __forceinline__ float fexp2(float x) {
#if __has_builtin(__builtin_amdgcn_exp2f)
    return __builtin_amdgcn_exp2f(x);
#else
    return exp2f(x);
#endif
}
__device__ __forceinline__ float frcp(float x) {
#if __has_builtin(__builtin_amdgcn_rcpf)
    return __builtin_amdgcn_rcpf(x);
#else
    return 1.0f / x;
#endif
}

// ---------------- detect int64 vs int32 edge_index layout ----------------
__global__ void k_detect(const int* __restrict__ ei, int* __restrict__ flag) {
    __shared__ int sor;
    if (threadIdx.x == 0) sor = 0;
    __syncthreads();
    int v = 0;
    for (int k = threadIdx.x; k < 1024; k += blockDim.x) v |= ei[2 * k + 1];
    atomicOr(&sor, v);
    __syncthreads();
    if (threadIdx.x == 0) flag[0] = (sor == 0) ? 1 : 0;  // 1 => int64 layout
}

__device__ __forceinline__ void load_edge(const int* __restrict__ ei, int E, int f64,
                                          int e, int& s, int& dd) {
    if (f64) { s = ei[2 * e]; dd = ei[2 * E + 2 * e]; }
    else     { s = ei[e];     dd = ei[E + e]; }
}

// ---------------- WTb[384][128] bf16 (B^T layout), BB[384] f32 ----------------
__global__ void k_wprep(const float* __restrict__ Wq, const float* __restrict__ bq,
                        const float* __restrict__ Wk, const float* __restrict__ bk,
                        const float* __restrict__ Wv, const float* __restrict__ bv,
                        ushort* __restrict__ WTb, float* __restrict__ BB) {
    int idx = blockIdx.x * blockDim.x + threadIdx.x;
    int total = 384 * 128;
    for (int i = idx; i < total; i += gridDim.x * blockDim.x) {
        int c = i >> 7;
        int d = i & 127;
        int m = c >> 7;
        int cl = c & 127;
        int h = cl >> 4, kk = cl & 15;
        const float* W = (m == 0) ? Wq : ((m == 1) ? Wk : Wv);
        WTb[i] = f2b(W[(h * D_ + d) * DK_ + kk]);
    }
    if (idx < 384) {
        int m = idx >> 7, cl = idx & 127;
        const float* b = (m == 0) ? bq : ((m == 1) ? bk : bv);
        BB[idx] = b[cl];
    }
}

// ---------------- LayerNorm -> bf16 xnb ----------------
__global__ __launch_bounds__(256)
void k_ln(const float2* __restrict__ x2, uint* __restrict__ xnb, int N) {
    int row = blockIdx.x * 4 + (threadIdx.x >> 6);
    if (row >= N) return;
    int lane = threadIdx.x & 63;
    float2 v = x2[(size_t)row * 64 + lane];
    float s = v.x + v.y;
    #pragma unroll
    for (int o = 1; o < 64; o <<= 1) s += __shfl_xor(s, o);
    float mu = s * (1.0f / 128.0f);
    float dx = v.x - mu, dy = v.y - mu;
    float s2 = dx * dx + dy * dy;
    #pragma unroll
    for (int o = 1; o < 64; o <<= 1) s2 += __shfl_xor(s2, o);
    float rs = rsqrtf(s2 * (1.0f / 128.0f) + 1e-5f);
    uint lo = f2b(dx * rs), hi = f2b(dy * rs);
    xnb[(size_t)row * 64 + lane] = (hi << 16) | lo;
}

// ---------------- MFMA GEMM: [N x 128] bf16 x [128 x 384] -> qnb / kvb(interleaved) ----------------
__global__ __launch_bounds__(256)
void k_gemm(const ushort* __restrict__ xnb, const ushort* __restrict__ WTb,
            const float* __restrict__ BB,
            ushort* __restrict__ qnb, ushort* __restrict__ kvb,
            int N) {
    __shared__ short As[128 * 128];
    __shared__ short Bs[128 * 128];
    int tid = threadIdx.x;
    int rowBlk = blockIdx.x, cb = blockIdx.y;

    short8 av[8], bv[8];
    int chunk = tid & 15;
    #pragma unroll
    for (int i = 0; i < 8; ++i) {
        int row = i * 16 + (tid >> 4);
        int gRow = rowBlk * 128 + row;
        if (gRow < N) av[i] = *(const short8*)(xnb + (size_t)gRow * 128 + chunk * 8);
        else          av[i] = short8{0, 0, 0, 0, 0, 0, 0, 0};
        int gCol = cb * 128 + row;
        bv[i] = *(const short8*)(WTb + (size_t)gCol * 128 + chunk * 8);
    }
    #pragma unroll
    for (int i = 0; i < 8; ++i) {
        int row = i * 16 + (tid >> 4);
        int widx = row * 128 + ((chunk * 8) ^ ((row & 7) * 8));
        *(short8*)&As[widx] = av[i];
        *(short8*)&Bs[widx] = bv[i];
    }
    __syncthreads();

    int wv = tid >> 6, lane = tid & 63;
    int wr = wv >> 1, wc = wv & 1;
    int l15 = lane & 15, g = lane >> 4;

    f32x4 acc[4][4];
    #pragma unroll
    for (int m = 0; m < 4; ++m)
        #pragma unroll
        for (int n = 0; n < 4; ++n) acc[m][n] = f32x4{0.f, 0.f, 0.f, 0.f};

    #pragma unroll
    for (int kt = 0; kt < 4; ++kt) {
        int kshort = kt * 32 + g * 8;
        short8 af[4], bf[4];
        #pragma unroll
        for (int m = 0; m < 4; ++m) {
            int r = wr * 64 + m * 16 + l15;
            af[m] = *(const short8*)&As[r * 128 + (kshort ^ ((r & 7) * 8))];
        }
        #pragma unroll
        for (int n = 0; n < 4; ++n) {
            int c = wc * 64 + n * 16 + l15;
            bf[n] = *(const short8*)&Bs[c * 128 + (kshort ^ ((c & 7) * 8))];
        }
        #pragma unroll
        for (int m = 0; m < 4; ++m)
            #pragma unroll
            for (int n = 0; n < 4; ++n)
                acc[m][n] = __builtin_amdgcn_mfma_f32_16x16x32_bf16(af[m], bf[n], acc[m][n], 0, 0, 0);
    }

    float bb[4];
    #pragma unroll
    for (int n = 0; n < 4; ++n) bb[n] = BB[cb * 128 + wc * 64 + n * 16 + l15];

    #pragma unroll
    for (int m = 0; m < 4; ++m) {
        int R0 = rowBlk * 128 + wr * 64 + m * 16 + g * 4;
        #pragma unroll
        for (int n = 0; n < 4; ++n) {
            int cl = wc * 64 + n * 16 + l15;
            #pragma unroll
            for (int r = 0; r < 4; ++r) {
                int row = R0 + r;
                if (row >= N) continue;
                float val = acc[m][n][r] + bb[n];
                if (cb == 0) {
                    qnb[(size_t)row * 128 + cl] = f2b(val);
                } else {
                    int off = ((cl >> 1) << 2) + (cl & 1) + ((cb == 2) ? 2 : 0);
                    kvb[(size_t)row * 256 + off] = f2b(val);
                }
            }
        }
    }
}

// ---------------- degree over senders + count over receivers + packed pairs ----------------
__global__ void k_deg_count(const int* __restrict__ ei, const float* __restrict__ w,
                            const int* __restrict__ flag, float* __restrict__ deg,
                            int* __restrict__ cnt, uint* __restrict__ pp, int E) {
    int f64 = flag[0];
    int i = blockIdx.x * blockDim.x + threadIdx.x;
    int stride = gridDim.x * blockDim.x;
    for (int e = i; e < E; e += stride) {
        int s, dd;
        load_edge(ei, E, f64, e, s, dd);
        atomicAdd(&deg[s], w[e]);
        atomicAdd(&cnt[dd], 1);
        pp[e] = (uint)s | ((uint)dd << 16);   // requires N <= 65536
    }
}

// ---------------- temporal table -> bf16 gkv[TBL][256] interleaved (nearest-sample) ----------------
__global__ __launch_bounds__(128)
void k_table(const float* __restrict__ Wk, const float* __restrict__ Wv,
             ushort* __restrict__ gkv) {
    __shared__ float te[8][128];
    int j = threadIdx.x;
    int t0 = blockIdx.x * 8;
    float freq = 200.0f * exp2f(-(float)(j >> 1) * (13.287712379549449f / 64.0f));
    bool isCos = (j & 1);
    #pragma unroll
    for (int b = 0; b < 8; ++b) {
        float t = (float)(t0 + b) * (1.0f / (float)(TBL - 1));
        float arg = t * freq;
        te[b][j] = isCos ? cosf(arg) : sinf(arg);
    }
    __syncthreads();
    int h = j >> 4, kk = j & 15;
    float ak[8] = {}, av[8] = {};
    for (int d = 0; d < 128; ++d) {
        float wk = Wk[(h * 128 + d) * 16 + kk];
        float wv = Wv[(h * 128 + d) * 16 + kk];
        float tvs[8];
        #pragma unroll
        for (int b = 0; b < 8; ++b) tvs[b] = te[b][d];
        #pragma unroll
        for (int b = 0; b < 8; ++b) { ak[b] += tvs[b] * wk; av[b] += tvs[b] * wv; }
    }
    int off = ((j >> 1) << 2) + (j & 1);
    #pragma unroll
    for (int b = 0; b < 8; ++b) {
        gkv[(size_t)(t0 + b) * 256 + off]     = f2b(ak[b]);
        gkv[(size_t)(t0 + b) * 256 + off + 2] = f2b(av[b]);
    }
}

// ---------------- 3-kernel exclusive scan over cnt -> rowptr (+cursor clone) ----------------
__global__ __launch_bounds__(256)
void k_scanA(const int* __restrict__ cnt, int* __restrict__ csum) {
    __shared__ int sh[256];
    int b = blockIdx.x, t = threadIdx.x;
    int base = b * 1024 + t * 4;
    int s = cnt[base] + cnt[base + 1] + cnt[base + 2] + cnt[base + 3];
    sh[t] = s;
    __syncthreads();
    for (int off = 128; off > 0; off >>= 1) {
        if (t < off) sh[t] += sh[t + off];
        __syncthreads();
    }
    if (t == 0) csum[b] = sh[0];
}

__global__ void k_scanB(int* __restrict__ csum, int nch) {
    if (blockIdx.x == 0 && threadIdx.x == 0) {
        int run = 0;
        for (int i = 0; i < nch; ++i) { int v = csum[i]; csum[i] = run; run += v; }
    }
}

__global__ __launch_bounds__(256)
void k_scanC(const int* __restrict__ cnt, const int* __restrict__ csum,
             int* __restrict__ rowptr, int* __restrict__ cursor) {
    __shared__ int sh[256];
    int b = blockIdx.x, t = threadIdx.x;
    int base = b * 1024 + t * 4;
    int v0 = cnt[base], v1 = cnt[base + 1], v2 = cnt[base + 2], v3 = cnt[base + 3];
    int tot = v0 + v1 + v2 + v3;
    sh[t] = tot;
    __syncthreads();
    for (int off = 1; off < 256; off <<= 1) {
        int add = (t >= off) ? sh[t - off] : 0;
        __syncthreads();
        sh[t] += add;
        __syncthreads();
    }
    int excl = sh[t] - tot + csum[b];
    rowptr[base]     = excl;
    rowptr[base + 1] = excl + v0;
    rowptr[base + 2] = excl + v0 + v1;
    rowptr[base + 3] = excl + v0 + v1 + v2;
    cursor[base]     = excl;
    cursor[base + 1] = excl + v0;
    cursor[base + 2] = excl + v0 + v1;
    cursor[base + 3] = excl + v0 + v1 + v2;
}

// ---------------- scatter packed 8B edge records into dst-CSR buckets ----------------
// record: {src | (table_idx<<16), ew*0.25*log2(e) float bits}
__global__ void k_scatter(const uint* __restrict__ pp, const float* __restrict__ ewt,
                          const float* __restrict__ etime, const float* __restrict__ deg,
                          int* __restrict__ cursor, uint2* __restrict__ erec, int E) {
    const float C = 0.25f * 1.4426950408889634f;
    int i = blockIdx.x * blockDim.x + threadIdx.x;
    int stride = gridDim.x * blockDim.x;
    for (int e = i; e < E; e += stride) {
        uint P = pp[e];
        int s = (int)(P & 0xffffu), dd = (int)(P >> 16);
        int pos = atomicAdd(&cursor[dd], 1);
        float t = etime[e];
        int ti = (int)(t * (float)(TBL - 1) + 0.5f);
        ti = ti < 0 ? 0 : (ti > TBL - 1 ? TBL - 1 : ti);
        float dg = deg[s];
        float ewc = dg > 0.f ? ewt[e] * C / dg : 0.f;
        uint2 r;
        r.x = (uint)s | ((uint)ti << 16);
        r.y = __float_as_uint(ewc);
        erec[pos] = r;
    }
}

// ---------------- fused per-node attention + aggregation + residual + GELU ----------------
__global__ __launch_bounds__(256)
void k_aggr(const int* __restrict__ rowptr, const uint2* __restrict__ erec,
            const ushort* __restrict__ qnb, const ushort* __restrict__ kvb,
            const ushort* __restrict__ gkv,
            const float2* __restrict__ x2, float2* __restrict__ out2, int N) {
    int w = (int)((blockIdx.x * (size_t)blockDim.x + threadIdx.x) >> 6);
    if (w >= N) return;
    int lane = threadIdx.x & 63;
    uint qv = *(const uint*)(qnb + (size_t)w * 128 + 2 * lane);
    float qx = blo(qv), qy = bhi(qv);
    float nx = 0.f, ny = 0.f, den = 0.f;
    int beg = rowptr[w], end = rowptr[w + 1];

    int j = beg;
    for (; j + 2 <= end; j += 2) {
        uint2 r0 = erec[j], r1 = erec[j + 1];
        uint2 kv0 = *(const uint2*)(kvb + (size_t)(r0.x & 0xffffu) * 256 + 4 * lane);
        uint2 g0  = *(const uint2*)(gkv + (size_t)(r0.x >> 16) * 256 + 4 * lane);
        uint2 kv1 = *(const uint2*)(kvb + (size_t)(r1.x & 0xffffu) * 256 + 4 * lane);
        uint2 g1  = *(const uint2*)(gkv + (size_t)(r1.x >> 16) * 256 + 4 * lane);

        float kx0 = blo(kv0.x) + blo(g0.x), ky0 = bhi(kv0.x) + bhi(g0.x);
        float kx1 = blo(kv1.x) + blo(g1.x), ky1 = bhi(kv1.x) + bhi(g1.x);
        float p0 = kx0 * qx + ky0 * qy;
        float p1 = kx1 * qx + ky1 * qy;
        p0 += __shfl_xor(p0, 1); p1 += __shfl_xor(p1, 1);
        p0 += __shfl_xor(p0, 2); p1 += __shfl_xor(p1, 2);
        p0 += __shfl_xor(p0, 4); p1 += __shfl_xor(p1, 4);
        float ex0 = fexp2(p0 * __uint_as_float(r0.y));
        float ex1 = fexp2(p1 * __uint_as_float(r1.y));
        den += ex0 + ex1;
        nx += ex0 * (blo(kv0.y) + blo(g0.y)) + ex1 * (blo(kv1.y) + blo(g1.y));
        ny += ex0 * (bhi(kv0.y) + bhi(g0.y)) + ex1 * (bhi(kv1.y) + bhi(g1.y));
    }
    if (j < end) {
        uint2 r0 = erec[j];
        uint2 kv0 = *(const uint2*)(kvb + (size_t)(r0.x & 0xffffu) * 256 + 4 * lane);
        uint2 g0  = *(const uint2*)(gkv + (size_t)(r0.x >> 16) * 256 + 4 * lane);
        float kx0 = blo(kv0.x) + blo(g0.x), ky0 = bhi(kv0.x) + bhi(g0.x);
        float p0 = kx0 * qx + ky0 * qy;
        p0 += __shfl_xor(p0, 1);
        p0 += __shfl_xor(p0, 2);
        p0 += __shfl_xor(p0, 4);
        float ex0 = fexp2(p0 * __uint_as_float(r0.y));
        den += ex0;
        nx += ex0 * (blo(kv0.y) + blo(g0.y));
        ny += ex0 * (bhi(kv0.y) + bhi(g0.y));
    }

    float inv = den > 0.f ? frcp(den) : 0.f;
    nx *= inv; ny *= inv;
    float2 xx = x2[(size_t)w * 64 + lane];
    float2 o;
    o.x = xx.x + 0.5f * nx * (1.0f + erff(nx * 0.70710678118f));
    o.y = xx.y + 0.5f * ny * (1.0f + erff(ny * 0.70710678118f));
    out2[(size_t)w * 64 + lane] = o;
}

extern "C" void kernel_launch(void* const* d_in, const int* in_sizes, int n_in,
                              void* d_out, int out_size, void* d_ws, size_t ws_size,
                              hipStream_t stream) {
    const float* x    = (const float*)d_in[0];
    const int*   ei   = (const int*)d_in[1];
    const float* ewt  = (const float*)d_in[2];
    const float* etim = (const float*)d_in[4];
    const float* Wk   = (const float*)d_in[5];
    const float* bk   = (const float*)d_in[6];
    const float* Wq   = (const float*)d_in[7];
    const float* bq   = (const float*)d_in[8];
    const float* Wv   = (const float*)d_in[9];
    const float* bv   = (const float*)d_in[10];
    int N = in_sizes[3];
    int E = in_sizes[2];
    float* out = (float*)d_out;

    int NCH = (N + 1 + 1023) / 1024;
    int NP = NCH * 1024;

    char* base = (char*)d_ws;
    size_t off = 0;
    auto alloc = [&](size_t bytes) {
        char* r = base + off;
        off += (bytes + 255) & ~size_t(255);
        return r;
    };
    ushort* xnb = (ushort*)alloc((size_t)N * 128 * 2);   // dead after gemm; reused as erec
    ushort* qnb = (ushort*)alloc((size_t)N * 128 * 2);
    ushort* kvb = (ushort*)alloc((size_t)N * 256 * 2);
    ushort* gkv = (ushort*)alloc((size_t)TBL * 256 * 2);
    ushort* WTb = (ushort*)alloc(384 * 128 * 2);
    float*  BB  = (float*)alloc(384 * 4);
    float*  deg = (float*)alloc((size_t)N * 4);
    uint*   pp  = (uint*)alloc((size_t)E * 4);
    int*    cnt    = (int*)alloc((size_t)NP * 4);
    int*    rowptr = (int*)alloc((size_t)NP * 4);
    int*    cursor = (int*)alloc((size_t)NP * 4);
    int*    csum   = (int*)alloc((size_t)NCH * 4);
    int*    flag   = (int*)alloc(16);
    uint2*  erec   = (uint2*)xnb;   // E*8 = 5.1MB <= N*256B = 12.8MB

    hipMemsetAsync(deg, 0, (size_t)N * sizeof(float), stream);
    hipMemsetAsync(cnt, 0, (size_t)NP * sizeof(int), stream);

    k_detect<<<1, 256, 0, stream>>>(ei, flag);
    k_wprep<<<64, 256, 0, stream>>>(Wq, bq, Wk, bk, Wv, bv, WTb, BB);
    k_deg_count<<<512, 256, 0, stream>>>(ei, ewt, flag, deg, cnt, pp, E);
    k_table<<<TBL / 8, 128, 0, stream>>>(Wk, Wv, gkv);
    k_ln<<<(N + 3) / 4, 256, 0, stream>>>((const float2*)x, (uint*)xnb, N);

    dim3 ggrid((N + 127) / 128, 3);
    k_gemm<<<ggrid, 256, 0, stream>>>(xnb, WTb, BB, qnb, kvb, N);

    k_scanA<<<NCH, 256, 0, stream>>>(cnt, csum);
    k_scanB<<<1, 64, 0, stream>>>(csum, NCH);
    k_scanC<<<NCH, 256, 0, stream>>>(cnt, csum, rowptr, cursor);
    k_scatter<<<512, 256, 0, stream>>>(pp, ewt, etim, deg, cursor, erec, E);

    int agrid = (int)(((size_t)N * 64 + 255) / 256);
    k_aggr<<<agrid, 256, 0, stream>>>(rowptr, erec, qnb, kvb, gkv,
                                      (const float2*)x, (float2*)out, N);
}